// Round 8
// baseline (800.057 us; speedup 1.0000x reference)
//
#include <hip/hip_runtime.h>
#include <math.h>

typedef unsigned short u16;
typedef __bf16 bf16x8 __attribute__((ext_vector_type(8)));
typedef float f32x4 __attribute__((ext_vector_type(4)));
typedef unsigned short u16x8 __attribute__((ext_vector_type(8)));

#define T_TOK 4096
#define DIMD 2048
#define HIDD 1024
#define NEXP 16
#define RMAX 10240
#define MAXBLK 96
#define BM 128
#define BN 128
#define BK 32

__device__ __forceinline__ u16 f2b(float f) {
  unsigned u = __builtin_bit_cast(unsigned, f);
  unsigned r = (u + 0x7FFFu + ((u >> 16) & 1u)) >> 16;  // RNE
  return (u16)r;
}

__device__ __forceinline__ void gld16(const void* g, void* l) {
  __builtin_amdgcn_global_load_lds(
      (const __attribute__((address_space(1))) void*)g,
      (__attribute__((address_space(3))) void*)l, 16, 0, 0);
}

// ---------------- small kernels ----------------

// fused: cvt(x->xb bf16) + init(perm/perm2/cnt)
__global__ void k_pre(const float* __restrict__ x, u16* __restrict__ xb,
                      int* __restrict__ perm, int* __restrict__ perm2,
                      int* __restrict__ cnt) {
  const int i = blockIdx.x * blockDim.x + threadIdx.x;
  const float4 v = ((const float4*)x)[i];
  union { u16 u[4]; unsigned long long q; } t;
  t.u[0] = f2b(v.x); t.u[1] = f2b(v.y); t.u[2] = f2b(v.z); t.u[3] = f2b(v.w);
  ((unsigned long long*)xb)[i] = t.q;
  if (i < RMAX) { perm[i] = -1; perm2[i] = -1; }
  if (i < NEXP) cnt[i] = 0;
}

// gating
__global__ __launch_bounds__(256)
void k_gate(const float* __restrict__ x, const float* __restrict__ gw,
            int* __restrict__ top2i, float* __restrict__ top2w,
            int* __restrict__ cnt, float* __restrict__ partial) {
  const int e = threadIdx.x & 15;
  const int tt = threadIdx.x >> 4;
  const int t = blockIdx.x * 16 + tt;
  const float* xp = x + (size_t)t * DIMD;
  float acc = 0.f;
#pragma unroll 8
  for (int k = 0; k < DIMD; ++k) acc = fmaf(xp[k], gw[k * NEXP + e], acc);
  __shared__ float lg[16][17];
  __shared__ float pr[16][17];
  lg[tt][e] = acc;
  __syncthreads();
  if (e == 0) {
    float l[16];
    float mx = -1e30f;
    for (int j = 0; j < 16; ++j) { l[j] = lg[tt][j]; mx = fmaxf(mx, l[j]); }
    float s = 0.f;
    for (int j = 0; j < 16; ++j) { l[j] = expf(l[j] - mx); s += l[j]; }
    const float inv = 1.f / s;
    float p1 = -1.f, p2 = -1.f; int i1 = 0, i2 = 0;
    for (int j = 0; j < 16; ++j) {
      const float p = l[j] * inv;
      pr[tt][j] = p;
      if (p > p1) { p2 = p1; i2 = i1; p1 = p; i1 = j; }
      else if (p > p2) { p2 = p; i2 = j; }
    }
    const float wsum = p1 + p2;
    top2i[t * 2 + 0] = i1;
    top2i[t * 2 + 1] = i2;
    top2w[t * 2 + 0] = p1 / wsum;
    top2w[t * 2 + 1] = p2 / wsum;
    atomicAdd(&cnt[i1], 1);
    atomicAdd(&cnt[i2], 1);
  }
  __syncthreads();
  if (tt == 0) {
    float s = 0.f;
    for (int j = 0; j < 16; ++j) s += pr[j][e];
    partial[blockIdx.x * 16 + e] = s;
  }
}

// merged scheduler: offsets+block-table (lane0), fill (LDS counters), aux.
__global__ __launch_bounds__(256)
void k_sched(const int* __restrict__ cnt, const int* __restrict__ top2i,
             const float* __restrict__ top2w, const float* __restrict__ partial,
             int* __restrict__ tbl_e, int* __restrict__ tbl_r0,
             int* __restrict__ nblk, int* __restrict__ perm,
             int* __restrict__ perm2, float* __restrict__ auxOut) {
  __shared__ int offs[17];
  __shared__ int lfill[16];
  __shared__ float s[16][17];
  const int tid = threadIdx.x;
  if (tid == 0) {
    int o = 0, nb = 0;
    for (int e = 0; e < NEXP; ++e) {
      offs[e] = o;
      const int b = (cnt[e] + BM - 1) / BM;
      for (int i = 0; i < b; ++i) { tbl_e[nb] = e; tbl_r0[nb] = o + i * BM; ++nb; }
      o += b * BM;
    }
    offs[16] = o;
    nblk[0] = nb;
  }
  if (tid < 16) lfill[tid] = 0;
  __syncthreads();
  for (int id = tid; id < T_TOK * 2; id += 256) {
    const int e = top2i[id];
    const int pos = atomicAdd(&lfill[e], 1);
    const int r = offs[e] + pos;
    perm[r] = id >> 1;   // token (A gather in k_up)
    perm2[r] = id;       // slot id (routed-down staging row)
  }
  const int e = tid & 15, c = tid >> 4;
  float a = 0.f;
  for (int b = c; b < 256; b += 16) a += partial[b * 16 + e];
  s[c][e] = a;
  __syncthreads();
  if (tid == 0) {
    float aux = 0.f;
    for (int j = 0; j < 16; ++j) {
      float tot = 0.f;
      for (int cc = 0; cc < 16; ++cc) tot += s[cc][j];
      const float m = tot / (float)T_TOK;
      aux += m * m;
    }
    auxOut[0] = aux * (float)NEXP;
  }
}

// merged weight transpose+convert. z-order chosen so w1 is transposed LAST
// (k_up reads it first -> L3-warm): z<16: w2 | 16,17: sw1 | 18,19: sw2 |
// 20..35: w1.
__global__ __launch_bounds__(256)
void k_trW(const float* __restrict__ w1, const float* __restrict__ w2,
           const float* __restrict__ sw1, const float* __restrict__ sw2,
           u16* __restrict__ w1t, u16* __restrict__ w2t,
           u16* __restrict__ sw1t, u16* __restrict__ sw2ct) {
  const int z = blockIdx.z;
  const float* W; u16* Wo; int K, N, ldo;
  if (z < 16) {
    W = w2 + (size_t)z * 1024 * 2048;  Wo = w2t + (size_t)z * 2048 * 1024;
    K = 1024; N = 2048; ldo = 1024;
  } else if (z < 18) {
    W = sw1 + (size_t)(z - 16) * 2048 * 1024;  Wo = sw1t + (size_t)(z - 16) * 1024 * 2048;
    K = 2048; N = 1024; ldo = 2048;
  } else if (z < 20) {
    W = sw2 + (size_t)(z - 18) * 1024 * 2048;  Wo = sw2ct + (size_t)(z - 18) * 1024;
    K = 1024; N = 2048; ldo = 2048;
  } else {
    W = w1 + (size_t)(z - 20) * 2048 * 1024;  Wo = w1t + (size_t)(z - 20) * 1024 * 2048;
    K = 2048; N = 1024; ldo = 2048;
  }
  const int n0 = blockIdx.x * 64, k0 = blockIdx.y * 64;
  if (n0 >= N || k0 >= K) return;
  __shared__ float t[64][65];
  {
    const int r = threadIdx.x >> 4;
    const int c = (threadIdx.x & 15) * 4;
#pragma unroll
    for (int p = 0; p < 4; ++p) {
      const int kk = p * 16 + r;
      const float4 v = *(const float4*)&W[(size_t)(k0 + kk) * N + n0 + c];
      t[kk][c] = v.x; t[kk][c + 1] = v.y; t[kk][c + 2] = v.z; t[kk][c + 3] = v.w;
    }
  }
  __syncthreads();
  {
    const int r2 = threadIdx.x >> 3;
    const int g8 = (threadIdx.x & 7) * 8;
#pragma unroll
    for (int p = 0; p < 2; ++p) {
      const int nn = p * 32 + r2;
      u16x8 o;
#pragma unroll
      for (int i = 0; i < 8; ++i) o[i] = f2b(t[g8 + i][nn]);
      *(u16x8*)&Wo[(size_t)(n0 + nn) * ldo + k0 + g8] = o;
    }
  }
}

// epilogue gather: out[t] += w(2t)*rb[2t] + w(2t+1)*rb[2t+1]
__global__ __launch_bounds__(512)
void k_post(float* __restrict__ out, const float* __restrict__ rb,
            const float* __restrict__ top2w) {
  const int t = blockIdx.x;
  const int d4 = threadIdx.x;
  const float w0 = top2w[t * 2], w1 = top2w[t * 2 + 1];
  const float4 a = ((const float4*)(rb + (size_t)(2 * t) * DIMD))[d4];
  const float4 b = ((const float4*)(rb + (size_t)(2 * t + 1) * DIMD))[d4];
  float4* op = (float4*)(out + (size_t)t * DIMD);
  float4 o = op[d4];
  o.x += w0 * a.x + w1 * b.x;
  o.y += w0 * a.y + w1 * b.y;
  o.z += w0 * a.z + w1 * b.z;
  o.w += w0 * a.w + w1 * b.w;
  op[d4] = o;
}

// ---------- GEMM core: high-residency counted-vmcnt ring-2 ----------
// 128x128 tile, BK=32, 256 threads (4 waves 2x2; 64x64 C per wave, acc[4][4]).
// LDS 32 KB total (ring-2 x {A 8KB + B 8KB}) -> 4+ blocks/CU co-resident:
// inter-block wave overlap (m114) hides the per-step barrier/vmcnt stalls.
// Swizzle: LDS(row, chunk c) holds global chunk c ^ ((row>>1)&3) (chunk=16B,
// 4/row). Staged via per-lane pre-swizzled GLOBAL source (linear LDS dest),
// read back with the same XOR -> 2 lanes/bank-group = conflict-free.
// Per K-step: {8 ds_read; 16 MFMA(setprio); BARR; stage t+2 (4 gld16);
// vmcnt(4); BARR}.  Counted vmcnt: t+1 landed, t+2's 4 in flight.

#define FENCE asm volatile("" ::: "memory")
#define VMW4  asm volatile("s_waitcnt vmcnt(4)" ::: "memory")
#define VMW0  asm volatile("s_waitcnt vmcnt(0)" ::: "memory")
#define BARR  do { FENCE; __builtin_amdgcn_s_barrier(); FENCE; } while (0)

// per-thread staging pointers (2 for A, 2 for B), precomputed with swizzle
struct SP { const u16* a[2]; const u16* b[2]; };

__device__ __forceinline__ void stage_t(const SP& sp, u16* S, int buf,
                                        int w, int k) {
  u16* As = S + buf * 8192;
  u16* Bs = As + 4096;
#pragma unroll
  for (int j = 0; j < 2; ++j) {
    gld16(sp.a[j] + k, As + (w * 2 + j) * 512);
    gld16(sp.b[j] + k, Bs + (w * 2 + j) * 512);
  }
}

__device__ __forceinline__ void comp_t(const u16* __restrict__ S, int buf,
    const int (&aoff)[4], const int (&boff)[4], f32x4 (&acc)[4][4]) {
  const u16* As = S + buf * 8192;
  bf16x8 af[4], bq[4];
#pragma unroll
  for (int i = 0; i < 4; ++i) af[i] = *(const bf16x8*)(As + aoff[i]);
#pragma unroll
  for (int j = 0; j < 4; ++j) bq[j] = *(const bf16x8*)(As + 4096 + boff[j]);
  __builtin_amdgcn_s_setprio(1);
#pragma unroll
  for (int i = 0; i < 4; ++i)
#pragma unroll
    for (int j = 0; j < 4; ++j)
      acc[i][j] = __builtin_amdgcn_mfma_f32_16x16x32_bf16(af[i], bq[j], acc[i][j], 0, 0, 0);
  __builtin_amdgcn_s_setprio(0);
}

__device__ __forceinline__ void gemm_r2(const SP& sp, int K, u16* S,
    const int (&aoff)[4], const int (&boff)[4], f32x4 (&acc)[4][4], int w) {
  const int nt = K >> 5;  // >= 32
  stage_t(sp, S, 0, w, 0);
  stage_t(sp, S, 1, w, BK);
  VMW4;                               // tile0 landed; tile1's 4 in flight
  BARR;
  int cur = 0;
  for (int t = 0; t < nt - 2; ++t) {
    comp_t(S, cur, aoff, boff, acc);
    BARR;                             // all waves done reading buf cur
    stage_t(sp, S, cur, w, (t + 2) << 5);
    VMW4;                             // t+1 landed; t+2 in flight
    BARR;
    cur ^= 1;
  }
  comp_t(S, cur, aoff, boff, acc);    // tile nt-2
  VMW0;                               // tile nt-1 landed
  BARR;
  comp_t(S, cur ^ 1, aoff, boff, acc);
}

// per-lane helpers for staging geometry
// instr (w,j) covers rows g16 = (w*2+j)*16 .. +15; lane -> row g16+(lane>>2),
// chunk lane&3; global src chunk = (lane&3) ^ ((row>>1)&3).

// Fused up-projection. Shared (bx<32): B=sw1t concat-n [2048][2048], out hbS.
// Routed (bx>=32, by<8): per-expert B=w1t[e] (N=1024), out hbR. K=2048.
__global__ __launch_bounds__(256, 4)
void k_up(const u16* __restrict__ xb, const u16* __restrict__ sw1t,
          const u16* __restrict__ w1t, u16* __restrict__ hbS,
          u16* __restrict__ hbR, const int* __restrict__ perm,
          const int* __restrict__ tbl_e, const int* __restrict__ tbl_r0,
          const int* __restrict__ nblk) {
  __shared__ u16 S[16384];  // 32 KB
  const int bx = blockIdx.x, by = blockIdx.y;
  const int tid = threadIdx.x;
  const int w = tid >> 6, lane = tid & 63;
  const int lm = lane & 15, lq = lane >> 4;
  const int wm = w >> 1, wn = w & 1;

  const bool routed = bx >= 32;
  int r0; const u16* Bb;
  if (!routed) {
    r0 = bx * BM;
    Bb = sw1t;
  } else {
    if (by >= 8) return;
    const int rbx = bx - 32;
    if (rbx >= *nblk) return;
    const int e = tbl_e[rbx];
    r0 = tbl_r0[rbx];
    Bb = w1t + (size_t)e * (size_t)HIDD * DIMD;
  }
  const int n0 = by * BN;

  SP sp;
#pragma unroll
  for (int j = 0; j < 2; ++j) {
    const int lrow = (w * 2 + j) * 16 + (lane >> 2);          // local row 0..127
    const int co = ((lane & 3) ^ ((lrow >> 1) & 3)) * 8;      // swizzled chunk
    int ga;
    if (!routed) ga = r0 + lrow;
    else { const int p = perm[r0 + lrow]; ga = (p < 0) ? 0 : p; }
    sp.a[j] = xb + (size_t)ga * DIMD + co;
    sp.b[j] = Bb + (size_t)(n0 + lrow) * DIMD + co;
  }
  int aoff[4], boff[4];
#pragma unroll
  for (int i = 0; i < 4; ++i) {
    const int ra = wm * 64 + i * 16 + lm;
    const int rb_ = wn * 64 + i * 16 + lm;
    aoff[i] = ra * 32 + ((lq ^ ((ra >> 1) & 3)) * 8);
    boff[i] = rb_ * 32 + ((lq ^ ((rb_ >> 1) & 3)) * 8);
  }
  f32x4 acc[4][4];
#pragma unroll
  for (int i = 0; i < 4; ++i)
#pragma unroll
    for (int j = 0; j < 4; ++j) {
      acc[i][j][0] = 0.f; acc[i][j][1] = 0.f; acc[i][j][2] = 0.f; acc[i][j][3] = 0.f;
    }

  gemm_r2(sp, DIMD, S, aoff, boff, acc, w);

#pragma unroll
  for (int i = 0; i < 4; ++i) {
#pragma unroll
    for (int r = 0; r < 4; ++r) {
      const int row = r0 + wm * 64 + i * 16 + lq * 4 + r;
      u16* dst = routed ? hbR + (size_t)row * HIDD : hbS + (size_t)row * DIMD;
#pragma unroll
      for (int j = 0; j < 4; ++j) {
        const int gc = n0 + wn * 64 + j * 16 + lm;
        const float v = acc[i][j][r];
        const float s = v / (1.f + expf(-v));
        dst[gc] = f2b(s);
      }
    }
  }
}

// Fused down-projection. Shared (bx<32): A=hbS K=2048 ld=2048, B=sw2ct,
// plain fp32 store to out. Routed (bx>=32): A=hbR K=1024 ld=1024, B=w2t[e],
// unweighted fp32 store by slot-id into rb (overlaid on dead w1t).
__global__ __launch_bounds__(256, 4)
void k_down(const u16* __restrict__ hbS, const u16* __restrict__ hbR,
            const u16* __restrict__ sw2ct, const u16* __restrict__ w2t,
            float* __restrict__ out, float* __restrict__ rb,
            const int* __restrict__ perm2, const int* __restrict__ tbl_e,
            const int* __restrict__ tbl_r0, const int* __restrict__ nblk) {
  __shared__ u16 S[16384];
  const int bx = blockIdx.x, by = blockIdx.y;
  const int tid = threadIdx.x;
  const int w = tid >> 6, lane = tid & 63;
  const int lm = lane & 15, lq = lane >> 4;
  const int wm = w >> 1, wn = w & 1;

  const bool routed = bx >= 32;
  int r0, K, ld;
  const u16 *Ab, *Bb;
  if (!routed) {
    r0 = bx * BM;
    Ab = hbS; K = DIMD; ld = DIMD;
    Bb = sw2ct;
  } else {
    const int rbx = bx - 32;
    if (rbx >= *nblk) return;
    const int e = tbl_e[rbx];
    r0 = tbl_r0[rbx];
    Ab = hbR; K = HIDD; ld = HIDD;
    Bb = w2t + (size_t)e * (size_t)DIMD * HIDD;
  }
  const int n0 = by * BN;

  SP sp;
#pragma unroll
  for (int j = 0; j < 2; ++j) {
    const int lrow = (w * 2 + j) * 16 + (lane >> 2);
    const int co = ((lane & 3) ^ ((lrow >> 1) & 3)) * 8;
    sp.a[j] = Ab + (size_t)(r0 + lrow) * ld + co;
    sp.b[j] = Bb + (size_t)(n0 + lrow) * ld + co;
  }
  int aoff[4], boff[4];
#pragma unroll
  for (int i = 0; i < 4; ++i) {
    const int ra = wm * 64 + i * 16 + lm;
    const int rb_ = wn * 64 + i * 16 + lm;
    aoff[i] = ra * 32 + ((lq ^ ((ra >> 1) & 3)) * 8);
    boff[i] = rb_ * 32 + ((lq ^ ((rb_ >> 1) & 3)) * 8);
  }
  f32x4 acc[4][4];
#pragma unroll
  for (int i = 0; i < 4; ++i)
#pragma unroll
    for (int j = 0; j < 4; ++j) {
      acc[i][j][0] = 0.f; acc[i][j][1] = 0.f; acc[i][j][2] = 0.f; acc[i][j][3] = 0.f;
    }

  gemm_r2(sp, K, S, aoff, boff, acc, w);

#pragma unroll
  for (int i = 0; i < 4; ++i) {
#pragma unroll
    for (int r = 0; r < 4; ++r) {
      const int row = r0 + wm * 64 + i * 16 + lq * 4 + r;
      if (!routed) {
        float* dst = out + (size_t)row * DIMD;
#pragma unroll
        for (int j = 0; j < 4; ++j)
          dst[n0 + wn * 64 + j * 16 + lm] = acc[i][j][r];
      } else {
        const int id2 = perm2[row];
        if (id2 >= 0) {
          float* dst = rb + (size_t)id2 * DIMD;
#pragma unroll
          for (int j = 0; j < 4; ++j)
            dst[n0 + wn * 64 + j * 16 + lm] = acc[i][j][r];
        }
      }
    }
  }
}

// ---------------- launch ----------------

extern "C" void kernel_launch(void* const* d_in, const int* in_sizes, int n_in,
                              void* d_out, int out_size, void* d_ws, size_t ws_size,
                              hipStream_t stream) {
  const float* x   = (const float*)d_in[0];
  const float* gw  = (const float*)d_in[1];
  const float* sw1 = (const float*)d_in[2];
  const float* sw2 = (const float*)d_in[3];
  const float* w1  = (const float*)d_in[4];
  const float* w2  = (const float*)d_in[5];
  float* out = (float*)d_out;

  char* ws = (char*)d_ws;
  u16* xb    = (u16*)(ws);                         // 16 MB
  u16* hbS   = (u16*)(ws + (size_t)( 16 << 20));   // 16 MB  [4096][2048]
  u16* hbR   = (u16*)(ws + (size_t)( 32 << 20));   // 20 MB  [10240][1024]
  u16* sw1t  = (u16*)(ws + (size_t)( 56 << 20));   //  8 MB  concat-n [2048][2048]
  u16* sw2ct = (u16*)(ws + (size_t)( 64 << 20));   //  8 MB  concat-k [2048][2048]
  u16* w1t   = (u16*)(ws + (size_t)( 72 << 20));   // 64 MB  (reused as rb)
  u16* w2t   = (u16*)(ws + (size_t)(136 << 20));   // 64 MB  [16][2048][1024]
  float* rb  = (float*)(ws + (size_t)( 72 << 20)); // 64 MB  [8192 slots][2048] fp32
  char* p = ws + (size_t)(200 << 20);
  int*   top2i   = (int*)p;    p += T_TOK * 2 * 4;
  float* top2w   = (float*)p;  p += T_TOK * 2 * 4;
  int*   perm    = (int*)p;    p += RMAX * 4;
  int*   perm2   = (int*)p;    p += RMAX * 4;
  int*   cnt     = (int*)p;    p += 16 * 4;
  int*   tbl_e   = (int*)p;    p += MAXBLK * 4;
  int*   tbl_r0  = (int*)p;    p += MAXBLK * 4;
  int*   nblk    = (int*)p;    p += 16 * 4;
  float* partial = (float*)p;  p += 256 * 16 * 4;

  k_pre<<<(T_TOK * DIMD / 4) / 256, 256, 0, stream>>>(x, xb, perm, perm2, cnt);
  k_gate<<<T_TOK / 16, 256, 0, stream>>>(x, gw, top2i, top2w, cnt, partial);
  k_sched<<<1, 256, 0, stream>>>(cnt, top2i, top2w, partial, tbl_e, tbl_r0,
                                 nblk, perm, perm2, out + (size_t)T_TOK * DIMD);
  k_trW<<<dim3(32, 32, 36), 256, 0, stream>>>(w1, w2, sw1, sw2,
                                              w1t, w2t, sw1t, sw2ct);
  // up: shared 32 m-blocks x 16 n + routed <=96 m-blocks x 8 n
  k_up<<<dim3(32 + MAXBLK, 16), 256, 0, stream>>>(xb, sw1t, w1t, hbS, hbR,
                                                  perm, tbl_e, tbl_r0, nblk);
  // down: shared 32 x 16 + routed <=96 x 16
  k_down<<<dim3(32 + MAXBLK, 16), 256, 0, stream>>>(hbS, hbR, sw2ct, w2t, out,
                                                    rb, perm2, tbl_e, tbl_r0, nblk);
  k_post<<<T_TOK, 512, 0, stream>>>(out, rb, top2w);
}